// Round 4
// baseline (2095.346 us; speedup 1.0000x reference)
//
#include <hip/hip_runtime.h>
#include <math.h>

#define HH 256
#define WW 512
#define CC 768
#define KW 129            // kept W modes (0..128)
#define NB 8
#define BS 96
#define MPC (KW*HH)       // modes per channel = 33024
#define K3M 64            // modes per K3 block

constexpr float SF = 0.00276213586400528f;   // 1/sqrt(131072)  forward ortho
constexpr float SI = 0.00552427172801056f;   // 2/sqrt(131072)  inverse ortho (x2 from packing)
constexpr float LAM = 0.01f;

// XOR swizzle for the 256-entry FFT buffers: kills the 8-way write conflicts of
// early Stockham stages while keeping contiguous runs >=16 conflict-free.
#define SWZ(i) ((i) ^ (((i) >> 4) & 0xF))
// Swizzle for the [k][r] transpose tile (stride-8-float2 access across k lanes
// was a 16-way conflict): spread bits 4..7 into bits 1..3 and bit 7 into bit 0.
#define TSWZ(i) ((i) ^ ((((i) >> 4) & 7) << 1) ^ (((i) >> 7) & 1))

__device__ inline float2 cadd(float2 a, float2 b) { return make_float2(a.x + b.x, a.y + b.y); }
__device__ inline float2 csub(float2 a, float2 b) { return make_float2(a.x - b.x, a.y - b.y); }
__device__ inline float2 cmul(float2 a, float2 b) {
    return make_float2(a.x * b.x - a.y * b.y, a.x * b.y + a.y * b.x);
}

// Wave-local LDS fence: the FFT buffers are strictly per-wave, so cross-lane
// visibility within the wave only needs in-order DS completion (lgkmcnt(0)),
// not a workgroup barrier. "memory" clobber + sched_barrier stop the compiler
// from moving LDS ops across it (rule #18).
__device__ inline void wsync() {
    __builtin_amdgcn_sched_barrier(0);
    asm volatile("s_waitcnt lgkmcnt(0)" ::: "memory");
    __builtin_amdgcn_sched_barrier(0);
}

// ---------------------------------------------------------------------------
// Twiddle table: radix-2 stage s in [0,8), m = 128>>s entries,
// tw[off(s)+p] = e^{sign*2*pi*i*p/(256>>s)}.  off = 0,128,192,224,240,248,252,254.
// ---------------------------------------------------------------------------
__device__ inline void gen_tw(float2* tw, int tid, int nthr, float sign) {
    for (int f = tid; f < 255; f += nthr) {
        int fm = f, n = 256;
        while (fm >= (n >> 1)) { fm -= (n >> 1); n >>= 1; }
        float sn, cs;
        __sincosf(sign * 6.283185307179586f * (float)fm / (float)n, &sn, &cs);
        tw[f] = make_float2(cs, sn);
    }
}

// ---------------------------------------------------------------------------
// 256-point Stockham FFT, two radix-2 stages fused per pass (register radix-4).
// One 64-lane wave per row; per-wave data => wave-local sync only (wsync).
// ---------------------------------------------------------------------------
__device__ inline void fft256x4(float2* s0, float2* s1, const float2* tw, int lane) {
    float2* src = s0;
    float2* dst = s1;
    int logls = 0;
    int offA = 0;
#pragma unroll
    for (int j = 0; j < 4; j++) {
        int ls = 1 << logls;            // 1,4,16,64
        int hm = 64 >> logls;           // 64/ls = entries of stage B
        int offB = offA + (128 >> logls);
        int q = lane & (ls - 1);
        int p = lane >> logls;
        float2 a0 = src[SWZ(lane)];
        float2 a1 = src[SWZ(lane + 64)];
        float2 a2 = src[SWZ(lane + 128)];
        float2 a3 = src[SWZ(lane + 192)];
        float2 wA0 = tw[offA + p];
        float2 wA1 = tw[offA + p + hm];
        float2 wB  = tw[offB + p];
        float2 e0 = cadd(a0, a2);
        float2 e1 = cmul(csub(a0, a2), wA0);
        float2 e2 = cadd(a1, a3);
        float2 e3 = cmul(csub(a1, a3), wA1);
        float2 f0 = cadd(e0, e2);
        float2 f1 = cmul(csub(e0, e2), wB);
        float2 f2 = cadd(e1, e3);
        float2 f3 = cmul(csub(e1, e3), wB);
        int o = q + ((p << logls) << 2);  // q + 4*p*ls
        dst[SWZ(o)]          = f0;
        dst[SWZ(o + ls)]     = f2;
        dst[SWZ(o + 2 * ls)] = f1;
        dst[SWZ(o + 3 * ls)] = f3;
        wsync();
        float2* tmp = src; src = dst; dst = tmp;
        offA = offB + hm;
        logls += 2;
    }
}

// ---------------------------------------------------------------------------
// K1: forward real FFT along W (512 real -> 129 complex), packed-real trick.
// ---------------------------------------------------------------------------
__global__ __launch_bounds__(512) void k1_rfftw(const float* __restrict__ x,
                                                float2* __restrict__ A) {
    __shared__ float2 b0[8][256];
    __shared__ float2 b1[8][256];
    __shared__ float2 tile[KW * 8];
    __shared__ float2 tw[255];
    __shared__ float2 ctw[129];

    int tid = threadIdx.x;
    gen_tw(tw, tid, 512, -1.0f);
    for (int f = tid; f < 129; f += 512) {
        float sn, cs;
        __sincosf(-6.283185307179586f * (float)f / 512.0f, &sn, &cs);
        ctw[f] = make_float2(cs, sn);
    }

    int r = tid >> 6;            // row 0..7 (= wave id)
    int lane = tid & 63;
    int blk = blockIdx.x;        // 0..24575
    int c = blk >> 5;            // channel
    int h0 = (blk & 31) << 3;    // first h of this block
    int h = h0 + r;

    const float4* xrow = (const float4*)(x + ((size_t)c * HH + h) * WW);
    float2* s0 = b0[r];
    float2* s1 = b1[r];

    for (int n = lane; n < 128; n += 64) {
        float4 v = xrow[n];
        s0[SWZ(2 * n)]     = make_float2(v.x * SF, v.y * SF);
        s0[SWZ(2 * n + 1)] = make_float2(v.z * SF, v.w * SF);
    }
    __syncthreads();   // cross-wave: tw/ctw tables written by all threads

    fft256x4(s0, s1, tw, lane);

    for (int k = lane; k <= 128; k += 64) {
        float2 Za = s0[SWZ(k & 255)];
        float2 Zb = s0[SWZ((256 - k) & 255)];
        float2 Xe = make_float2(0.5f * (Za.x + Zb.x), 0.5f * (Za.y - Zb.y));
        float dx = Za.x - Zb.x;
        float dy = Za.y + Zb.y;
        float2 Xo = make_float2(0.5f * dy, -0.5f * dx);
        float2 X = cadd(Xe, cmul(Xo, ctw[k]));
        tile[TSWZ(k * 8 + r)] = X;
    }
    __syncthreads();   // cross-wave: transpose tile

    for (int idx = tid; idx < KW * 8; idx += 512) {
        int k = idx >> 3;
        int r2 = idx & 7;
        A[((size_t)c * KW + k) * HH + h0 + r2] = tile[TSWZ(idx)];
    }
}

// ---------------------------------------------------------------------------
// K2/K4: 256-pt complex FFT along H, in place. 4 columns per 256-thread block.
// ---------------------------------------------------------------------------
template <int SIGN>
__global__ __launch_bounds__(256) void k_colfft(float2* __restrict__ A) {
    __shared__ float2 b0[4][256];
    __shared__ float2 b1[4][256];
    __shared__ float2 tw[255];
    int tid = threadIdx.x;
    gen_tw(tw, tid, 256, (float)SIGN);
    int col = tid >> 6;          // 0..3 (= wave id)
    int lane = tid & 63;
    size_t base = ((size_t)blockIdx.x * 4 + col) * 256;
    float2* s0 = b0[col];
    float2* s1 = b1[col];
    const float4* Ai = (const float4*)(A + base);
    for (int n = lane; n < 128; n += 64) {
        float4 v = Ai[n];
        s0[SWZ(2 * n)]     = make_float2(v.x, v.y);
        s0[SWZ(2 * n + 1)] = make_float2(v.z, v.w);
    }
    __syncthreads();   // cross-wave: tw table
    fft256x4(s0, s1, tw, lane);
    float4* Ao = (float4*)(A + base);
    for (int n = lane; n < 128; n += 64) {
        float2 z0 = s0[SWZ(2 * n)];
        float2 z1 = s0[SWZ(2 * n + 1)];
        Ao[n] = make_float4(z0.x, z0.y, z1.x, z1.y);
    }
}

// ---------------------------------------------------------------------------
// K3 v4: per-mode complex MLP. Round-3 PMC: LDS pipe still 2:1 over VALU (the
// two broadcast weight reads). v4 moves weights to the VMEM pipe: per-lane
// (not readfirstlane -> stays vector) global_load_dwordx4 of 4 consecutive
// complex weights, coalesced to one 16B L1/L2 request, counted on vmcnt --
// independent of the ds_read lgkmcnt stream. Inner K-step = 1 ds_read_b64 +
// 2 VMEM loads + 16 FMA => LDS 96 cyc/CU < VALU 128 cyc wall: VALU-bound.
// No wt tile: LDS 48 KB -> 3 blocks/CU; barriers 12 -> 3.
// ---------------------------------------------------------------------------
__global__ __launch_bounds__(512, 4) void k3_mlp(float2* __restrict__ A,
                                                 const float2* __restrict__ w1,
                                                 const float2* __restrict__ b1,
                                                 const float2* __restrict__ w2,
                                                 const float2* __restrict__ b2) {
    __shared__ float2 tile[BS][K3M];   // 96 x 64 complex = 48 KB, a then hidden
    int tid = threadIdx.x;
    int bk = blockIdx.x / (MPC / K3M);           // 0..7
    int m0 = (blockIdx.x % (MPC / K3M)) * K3M;   // mode tile origin
    int t = tid & 63;
    int osu = tid >> 6;    // wave id 0..7 -- kept as VECTOR value on purpose
    int ob = osu * 4;      // wave's 4 outputs per phase

    // stage a-tile (each row = 64 consecutive modes, float4 both sides)
    for (int idx = tid; idx < BS * (K3M / 2); idx += 512) {
        int i = idx >> 5;
        int tt = idx & 31;
        float4 v = *(const float4*)(A + ((size_t)(bk * BS + i)) * MPC + m0 + 2 * tt);
        *(float4*)&tile[i][2 * tt] = v;
    }

    const float2* w1b = w1 + (size_t)bk * BS * BS;
    const float2* b1b = b1 + (size_t)bk * BS;
    const float2* w2b = w2 + (size_t)bk * BS * BS;
    const float2* b2b = b2 + (size_t)bk * BS;

    __syncthreads();

    float2 hreg[12];
    // ---- layer 1: h = relu(W1^T a + b1), 3 phases x (8 waves x 4 outputs) ----
#pragma unroll
    for (int ph = 0; ph < 3; ph++) {
        int o0 = ph * 32 + ob;
        const float2* wp = w1b + o0;
        float2 acc0 = b1b[o0];
        float2 acc1 = b1b[o0 + 1];
        float2 acc2 = b1b[o0 + 2];
        float2 acc3 = b1b[o0 + 3];
#pragma unroll 4
        for (int i = 0; i < BS; i++) {
            float2 a  = tile[i][t];
            float4 w01 = *(const float4*)(wp + (size_t)i * BS);       // o0, o0+1
            float4 w23 = *(const float4*)(wp + (size_t)i * BS + 2);   // o0+2, o0+3
            acc0.x = fmaf(a.x, w01.x, fmaf(-a.y, w01.y, acc0.x));
            acc0.y = fmaf(a.x, w01.y, fmaf(a.y, w01.x, acc0.y));
            acc1.x = fmaf(a.x, w01.z, fmaf(-a.y, w01.w, acc1.x));
            acc1.y = fmaf(a.x, w01.w, fmaf(a.y, w01.z, acc1.y));
            acc2.x = fmaf(a.x, w23.x, fmaf(-a.y, w23.y, acc2.x));
            acc2.y = fmaf(a.x, w23.y, fmaf(a.y, w23.x, acc2.y));
            acc3.x = fmaf(a.x, w23.z, fmaf(-a.y, w23.w, acc3.x));
            acc3.y = fmaf(a.x, w23.w, fmaf(a.y, w23.z, acc3.y));
        }
        hreg[ph * 4 + 0] = make_float2(fmaxf(acc0.x, 0.f), fmaxf(acc0.y, 0.f));
        hreg[ph * 4 + 1] = make_float2(fmaxf(acc1.x, 0.f), fmaxf(acc1.y, 0.f));
        hreg[ph * 4 + 2] = make_float2(fmaxf(acc2.x, 0.f), fmaxf(acc2.y, 0.f));
        hreg[ph * 4 + 3] = make_float2(fmaxf(acc3.x, 0.f), fmaxf(acc3.y, 0.f));
    }
    __syncthreads();   // all waves done reading a-tile
#pragma unroll
    for (int ph = 0; ph < 3; ph++) {
        int o = ph * 32 + ob;
        tile[o][t]     = hreg[ph * 4 + 0];
        tile[o + 1][t] = hreg[ph * 4 + 1];
        tile[o + 2][t] = hreg[ph * 4 + 2];
        tile[o + 3][t] = hreg[ph * 4 + 3];
    }
    __syncthreads();   // h-tile visible to all waves

    // ---- layer 2: s = softshrink(W2^T h + b2) ----
#pragma unroll
    for (int ph = 0; ph < 3; ph++) {
        int o0 = ph * 32 + ob;
        const float2* wp = w2b + o0;
        float2 acc0 = b2b[o0];
        float2 acc1 = b2b[o0 + 1];
        float2 acc2 = b2b[o0 + 2];
        float2 acc3 = b2b[o0 + 3];
#pragma unroll 4
        for (int i = 0; i < BS; i++) {
            float2 a  = tile[i][t];
            float4 w01 = *(const float4*)(wp + (size_t)i * BS);
            float4 w23 = *(const float4*)(wp + (size_t)i * BS + 2);
            acc0.x = fmaf(a.x, w01.x, fmaf(-a.y, w01.y, acc0.x));
            acc0.y = fmaf(a.x, w01.y, fmaf(a.y, w01.x, acc0.y));
            acc1.x = fmaf(a.x, w01.z, fmaf(-a.y, w01.w, acc1.x));
            acc1.y = fmaf(a.x, w01.w, fmaf(a.y, w01.z, acc1.y));
            acc2.x = fmaf(a.x, w23.x, fmaf(-a.y, w23.y, acc2.x));
            acc2.y = fmaf(a.x, w23.y, fmaf(a.y, w23.x, acc2.y));
            acc3.x = fmaf(a.x, w23.z, fmaf(-a.y, w23.w, acc3.x));
            acc3.y = fmaf(a.x, w23.w, fmaf(a.y, w23.z, acc3.y));
        }
        float2 accs[4] = {acc0, acc1, acc2, acc3};
#pragma unroll
        for (int j = 0; j < 4; j++) {
            float rx = fmaxf(fabsf(accs[j].x) - LAM, 0.f);
            float ry = fmaxf(fabsf(accs[j].y) - LAM, 0.f);
            float2 sv = make_float2(copysignf(rx, accs[j].x), copysignf(ry, accs[j].y));
            A[((size_t)(bk * BS + o0 + j)) * MPC + m0 + t] = sv;
        }
    }
}

// ---------------------------------------------------------------------------
// K5: inverse real FFT along W (129 complex modes -> 512 real), + x bias.
// ---------------------------------------------------------------------------
__global__ __launch_bounds__(512) void k5_irfftw(const float2* __restrict__ A,
                                                 const float* __restrict__ x,
                                                 float* __restrict__ out) {
    __shared__ float2 b0[8][256];
    __shared__ float2 b1[8][256];
    __shared__ float2 tile[KW * 8];
    __shared__ float2 tw[255];
    __shared__ float2 ctw[256];

    int tid = threadIdx.x;
    gen_tw(tw, tid, 512, 1.0f);
    for (int f = tid; f < 256; f += 512) {
        float sn, cs;
        __sincosf(6.283185307179586f * (float)f / 512.0f, &sn, &cs);
        ctw[f] = make_float2(cs, sn);
    }

    int blk = blockIdx.x;
    int c = blk >> 5;
    int h0 = (blk & 31) << 3;

    for (int idx = tid; idx < KW * 8; idx += 512) {
        int k = idx >> 3;
        int r2 = idx & 7;
        tile[TSWZ(idx)] = A[((size_t)c * KW + k) * HH + h0 + r2];
    }
    __syncthreads();   // cross-wave: tile + tw/ctw tables

    int r = tid >> 6;
    int lane = tid & 63;
    int h = h0 + r;
    float2* s0 = b0[r];
    float2* s1 = b1[r];

    for (int k = lane; k < 256; k += 64) {
        float2 P = make_float2(0.f, 0.f);
        float2 Q = make_float2(0.f, 0.f);
        if (k <= 128) {
            P = tile[TSWZ(k * 8 + r)];
            if (k == 0) P.y = 0.f;            // numpy irfft drops Im(DC)
        }
        if (k >= 128) {                        // X[k+256] = conj(X[256-k])
            float2 qv = tile[TSWZ((256 - k) * 8 + r)];
            Q = make_float2(qv.x, -qv.y);
        }
        float2 Xe = make_float2(0.5f * (P.x + Q.x), 0.5f * (P.y + Q.y));
        float2 d = make_float2(0.5f * (P.x - Q.x), 0.5f * (P.y - Q.y));
        float2 Xo = cmul(d, ctw[k]);
        s0[SWZ(k)] = make_float2(Xe.x - Xo.y, Xe.y + Xo.x);
    }
    wsync();   // per-wave: s0 written by own wave only

    fft256x4(s0, s1, tw, lane);   // unnormalized inverse, result in s0

    const float4* xr = (const float4*)(x + ((size_t)c * HH + h) * WW);
    float4* orow = (float4*)(out + ((size_t)c * HH + h) * WW);
    for (int m = lane; m < 128; m += 64) {
        float2 z0 = s0[SWZ(2 * m)];
        float2 z1 = s0[SWZ(2 * m + 1)];
        float4 xv = xr[m];
        orow[m] = make_float4(fmaf(SI, z0.x, xv.x), fmaf(SI, z0.y, xv.y),
                              fmaf(SI, z1.x, xv.z), fmaf(SI, z1.y, xv.w));
    }
}

// ---------------------------------------------------------------------------
extern "C" void kernel_launch(void* const* d_in, const int* in_sizes, int n_in,
                              void* d_out, int out_size, void* d_ws, size_t ws_size,
                              hipStream_t stream) {
    const float* x = (const float*)d_in[0];
    const float2* w1 = (const float2*)d_in[1];
    const float2* b1 = (const float2*)d_in[2];
    const float2* w2 = (const float2*)d_in[3];
    const float2* b2 = (const float2*)d_in[4];
    float* out = (float*)d_out;
    float2* A = (float2*)d_ws;   // [768][129][256] complex = 202,899,456 bytes

    k1_rfftw<<<dim3(CC * HH / 8), dim3(512), 0, stream>>>(x, A);
    k_colfft<-1><<<dim3(CC * KW / 4), dim3(256), 0, stream>>>(A);
    k3_mlp<<<dim3(NB * (MPC / K3M)), dim3(512), 0, stream>>>(A, w1, b1, w2, b2);
    k_colfft<1><<<dim3(CC * KW / 4), dim3(256), 0, stream>>>(A);
    k5_irfftw<<<dim3(CC * HH / 8), dim3(512), 0, stream>>>(A, x, out);
}